// Round 1
// baseline (154.458 us; speedup 1.0000x reference)
//
#include <hip/hip_runtime.h>

#define NND 50000
#define NED 500000
#define F0 64
#define F1 128
#define NCLS 4
#define NG 8

// capacities for compacted frontiers (expected: n2~80, e2~800, n1~800, e1~8000)
#define N1CAP 16384
#define N2CAP 4096
#define E1CAP 262144
#define E2CAP 65536
#define E3CAP 16384

// cnts layout: [0]=n1, [1]=n2, [2]=e1, [3]=e2, [4]=e3

__device__ __forceinline__ void claim_node(int* idx, int s, unsigned* cnt,
                                           int* nodelist, int cap) {
    if (atomicCAS(&idx[s], -1, -2) == -1) {
        unsigned id = atomicAdd(cnt, 1u);
        if ((int)id < cap) { nodelist[id] = s; atomicExch(&idx[s], (int)id); }
        else { atomicExch(&idx[s], -1); }
    }
}

__global__ void k_deg(const int* __restrict__ src, const int* __restrict__ dst,
                      unsigned* outcnt, unsigned* incnt) {
    int i = blockIdx.x * blockDim.x + threadIdx.x;
    if (i >= NED) return;
    atomicAdd(&outcnt[src[i]], 1u);
    atomicAdd(&incnt[dst[i]], 1u);
}

// mark target nodes; detect int32 vs int64 batch_num_nodes
__global__ void k_mark(const int* __restrict__ tnode, const unsigned* __restrict__ bnn,
                       int* tgtmap, int* tgtnode) {
    int g = threadIdx.x;
    if (g >= NG) return;
    // If batch_num_nodes is int64, the high words (odd indices among first 8 u32)
    // are all 0 (values ~6250). If int32, those words hold nonzero counts.
    bool is64 = true;
    for (int i = 0; i < 4; i++) if (bnn[2 * i + 1] != 0u) { is64 = false; break; }
    long long off = 0;
    for (int i = 0; i < g; i++)
        off += is64 ? (long long)bnn[2 * i] : (long long)(int)bnn[i];
    int t = tnode[g] + (int)off;
    tgtmap[t] = g;
    tgtnode[g] = t;
}

__global__ void k_pass3(const int* __restrict__ src, const int* __restrict__ dst,
                        const int* __restrict__ tgtmap, int* idx2, int* node2,
                        int* list3, unsigned* cnts) {
    int i = blockIdx.x * blockDim.x + threadIdx.x;
    if (i >= NED) return;
    int d = dst[i];
    if (tgtmap[d] >= 0) {
        unsigned p = atomicAdd(&cnts[4], 1u);
        if (p < E3CAP) list3[p] = i;
        claim_node(idx2, src[i], &cnts[1], node2, N2CAP);
    }
}

__global__ void k_pass2(const int* __restrict__ src, const int* __restrict__ dst,
                        const int* __restrict__ idx2, int* idx1, int* node1,
                        int* list2, unsigned* cnts) {
    int i = blockIdx.x * blockDim.x + threadIdx.x;
    if (i >= NED) return;
    int d = dst[i];
    if (idx2[d] >= 0) {
        unsigned p = atomicAdd(&cnts[3], 1u);
        if (p < E2CAP) list2[p] = i;
        claim_node(idx1, src[i], &cnts[0], node1, N1CAP);
    }
}

__global__ void k_pass1(const int* __restrict__ dst, const int* __restrict__ idx1,
                        int* list1, unsigned* cnts) {
    int i = blockIdx.x * blockDim.x + threadIdx.x;
    if (i >= NED) return;
    if (idx1[dst[i]] >= 0) {
        unsigned p = atomicAdd(&cnts[2], 1u);
        if (p < E1CAP) list1[p] = i;
    }
}

// aggregate in_feat into agg1c over edges in list1; one 64-lane wave per edge
__global__ void k_agg1(const float* __restrict__ feat, const float* __restrict__ ew,
                       const int* __restrict__ src, const int* __restrict__ dst,
                       const unsigned* __restrict__ outcnt, const int* __restrict__ idx1,
                       const int* __restrict__ list1, const unsigned* __restrict__ cnts,
                       float* agg1c) {
    unsigned e1 = cnts[2]; if (e1 > E1CAP) e1 = E1CAP;
    int lane = threadIdx.x & 63;
    unsigned slot = (blockIdx.x * blockDim.x + threadIdx.x) >> 6;
    unsigned nslots = (gridDim.x * blockDim.x) >> 6;
    for (unsigned i = slot; i < e1; i += nslots) {
        int e = list1[i];
        int s = src[e], d = dst[e];
        float w = ew[e] * rsqrtf(fmaxf((float)outcnt[s], 1.f));
        atomicAdd(&agg1c[(size_t)idx1[d] * F0 + lane], feat[(size_t)s * F0 + lane] * w);
    }
}

// h1 = relu(in_norm * agg1 @ W1 + b1); one node per block iteration, 128 threads
__global__ void k_h1(const float* __restrict__ W1, const float* __restrict__ b1,
                     const unsigned* __restrict__ incnt, const int* __restrict__ node1,
                     const unsigned* __restrict__ cnts, const float* __restrict__ agg1c,
                     float* h1c) {
    __shared__ float a[F0];
    unsigned n1 = cnts[0]; if (n1 > N1CAP) n1 = N1CAP;
    int j = threadIdx.x;
    for (unsigned i = blockIdx.x; i < n1; i += gridDim.x) {
        int v = node1[i];
        float innorm = rsqrtf(fmaxf((float)incnt[v], 1.f));
        if (j < F0) a[j] = agg1c[(size_t)i * F0 + j] * innorm;
        __syncthreads();
        float acc = b1[j];
        #pragma unroll
        for (int k = 0; k < F0; k++) acc += a[k] * W1[k * F1 + j];
        h1c[(size_t)i * F1 + j] = fmaxf(acc, 0.f);
        __syncthreads();
    }
}

// aggregate h1 into agg2c over edges in list2; 128-thread group per edge
__global__ void k_agg2(const float* __restrict__ ew, const int* __restrict__ src,
                       const int* __restrict__ dst, const unsigned* __restrict__ outcnt,
                       const int* __restrict__ idx1, const int* __restrict__ idx2,
                       const int* __restrict__ list2, const unsigned* __restrict__ cnts,
                       const float* __restrict__ h1c, float* agg2c) {
    unsigned e2 = cnts[3]; if (e2 > E2CAP) e2 = E2CAP;
    int j = threadIdx.x & 127;
    unsigned slot = (blockIdx.x * blockDim.x + threadIdx.x) >> 7;
    unsigned nslots = (gridDim.x * blockDim.x) >> 7;
    for (unsigned i = slot; i < e2; i += nslots) {
        int e = list2[i];
        int s = src[e], d = dst[e];
        float w = ew[e] * rsqrtf(fmaxf((float)outcnt[s], 1.f));
        atomicAdd(&agg2c[(size_t)idx2[d] * F1 + j], h1c[(size_t)idx1[s] * F1 + j] * w);
    }
}

// h2 = relu(in_norm * agg2 @ W2 + b2)
__global__ void k_h2(const float* __restrict__ W2, const float* __restrict__ b2,
                     const unsigned* __restrict__ incnt, const int* __restrict__ node2,
                     const unsigned* __restrict__ cnts, const float* __restrict__ agg2c,
                     float* h2c) {
    __shared__ float a[F1];
    unsigned n2 = cnts[1]; if (n2 > N2CAP) n2 = N2CAP;
    int j = threadIdx.x;
    for (unsigned i = blockIdx.x; i < n2; i += gridDim.x) {
        int v = node2[i];
        float innorm = rsqrtf(fmaxf((float)incnt[v], 1.f));
        a[j] = agg2c[(size_t)i * F1 + j] * innorm;
        __syncthreads();
        float acc = b2[j];
        #pragma unroll
        for (int k = 0; k < F1; k++) acc += a[k] * W2[k * F1 + j];
        h2c[(size_t)i * F1 + j] = fmaxf(acc, 0.f);
        __syncthreads();
    }
}

// aggregate h2 into agg3 (per target graph slot) over edges in list3
__global__ void k_agg3(const float* __restrict__ ew, const int* __restrict__ src,
                       const int* __restrict__ dst, const unsigned* __restrict__ outcnt,
                       const int* __restrict__ idx2, const int* __restrict__ tgtmap,
                       const int* __restrict__ list3, const unsigned* __restrict__ cnts,
                       const float* __restrict__ h2c, float* agg3) {
    unsigned e3 = cnts[4]; if (e3 > E3CAP) e3 = E3CAP;
    int j = threadIdx.x & 127;
    unsigned slot = (blockIdx.x * blockDim.x + threadIdx.x) >> 7;
    unsigned nslots = (gridDim.x * blockDim.x) >> 7;
    for (unsigned i = slot; i < e3; i += nslots) {
        int e = list3[i];
        int s = src[e], d = dst[e];
        int g = tgtmap[d];
        float w = ew[e] * rsqrtf(fmaxf((float)outcnt[s], 1.f));
        atomicAdd(&agg3[(size_t)g * F1 + j], h2c[(size_t)idx2[s] * F1 + j] * w);
    }
}

// out[g,c] = in_norm[tgt_g] * (agg3[g] @ W3)[c] + b3[c]
__global__ void k_out(const float* __restrict__ W3, const float* __restrict__ b3,
                      const unsigned* __restrict__ incnt, const int* __restrict__ tgtnode,
                      const float* __restrict__ agg3, float* out) {
    int t = threadIdx.x;
    if (t >= NG * NCLS) return;
    int g = t >> 2, c = t & 3;
    float innorm = rsqrtf(fmaxf((float)incnt[tgtnode[g]], 1.f));
    float s = 0.f;
    for (int k = 0; k < F1; k++) s += agg3[g * F1 + k] * W3[k * NCLS + c];
    out[t] = s * innorm + b3[c];
}

extern "C" void kernel_launch(void* const* d_in, const int* in_sizes, int n_in,
                              void* d_out, int out_size, void* d_ws, size_t ws_size,
                              hipStream_t stream) {
    const float* in_feat = (const float*)d_in[0];
    const float* ew      = (const float*)d_in[1];
    const int*   src     = (const int*)d_in[2];
    const int*   dst     = (const int*)d_in[3];
    const unsigned* bnn  = (const unsigned*)d_in[4];
    const int*   tnode   = (const int*)d_in[5];
    const float* W1 = (const float*)d_in[6];
    const float* b1 = (const float*)d_in[7];
    const float* W2 = (const float*)d_in[8];
    const float* b2 = (const float*)d_in[9];
    const float* W3 = (const float*)d_in[10];
    const float* b3 = (const float*)d_in[11];
    float* out = (float*)d_out;
    (void)in_sizes; (void)n_in; (void)out_size; (void)ws_size;

    char* ws = (char*)d_ws;
    size_t o = 0;
    auto alloc = [&](size_t bytes) { size_t r = o; o += (bytes + 255) & ~(size_t)255; return r; };

    // --- zero-init region (contiguous) ---
    size_t zero_start = o;
    size_t off_outcnt = alloc((size_t)NND * 4);
    size_t off_incnt  = alloc((size_t)NND * 4);
    size_t off_cnts   = alloc(8 * 4);
    size_t off_agg1   = alloc((size_t)N1CAP * F0 * 4);
    size_t off_agg2   = alloc((size_t)N2CAP * F1 * 4);
    size_t off_agg3   = alloc((size_t)NG * F1 * 4);
    size_t zero_bytes = o - zero_start;
    // --- 0xFF-init region (contiguous) ---
    size_t ff_start = o;
    size_t off_tgtmap = alloc((size_t)NND * 4);
    size_t off_idx2   = alloc((size_t)NND * 4);
    size_t off_idx1   = alloc((size_t)NND * 4);
    size_t ff_bytes = o - ff_start;
    // --- write-before-read region ---
    size_t off_node2   = alloc((size_t)N2CAP * 4);
    size_t off_node1   = alloc((size_t)N1CAP * 4);
    size_t off_list3   = alloc((size_t)E3CAP * 4);
    size_t off_list2   = alloc((size_t)E2CAP * 4);
    size_t off_list1   = alloc((size_t)E1CAP * 4);
    size_t off_tgtnode = alloc((size_t)NG * 4);
    size_t off_h1      = alloc((size_t)N1CAP * F1 * 4);
    size_t off_h2      = alloc((size_t)N2CAP * F1 * 4);

    unsigned* outcnt  = (unsigned*)(ws + off_outcnt);
    unsigned* incnt   = (unsigned*)(ws + off_incnt);
    unsigned* cnts    = (unsigned*)(ws + off_cnts);
    float*    agg1c   = (float*)(ws + off_agg1);
    float*    agg2c   = (float*)(ws + off_agg2);
    float*    agg3    = (float*)(ws + off_agg3);
    int*      tgtmap  = (int*)(ws + off_tgtmap);
    int*      idx2    = (int*)(ws + off_idx2);
    int*      idx1    = (int*)(ws + off_idx1);
    int*      node2   = (int*)(ws + off_node2);
    int*      node1   = (int*)(ws + off_node1);
    int*      list3   = (int*)(ws + off_list3);
    int*      list2   = (int*)(ws + off_list2);
    int*      list1   = (int*)(ws + off_list1);
    int*      tgtnode = (int*)(ws + off_tgtnode);
    float*    h1c     = (float*)(ws + off_h1);
    float*    h2c     = (float*)(ws + off_h2);

    hipMemsetAsync(ws + zero_start, 0, zero_bytes, stream);
    hipMemsetAsync(ws + ff_start, 0xFF, ff_bytes, stream);

    const int TB = 256;
    const int EG = (NED + TB - 1) / TB;

    k_deg<<<EG, TB, 0, stream>>>(src, dst, outcnt, incnt);
    k_mark<<<1, 64, 0, stream>>>(tnode, bnn, tgtmap, tgtnode);
    k_pass3<<<EG, TB, 0, stream>>>(src, dst, tgtmap, idx2, node2, list3, cnts);
    k_pass2<<<EG, TB, 0, stream>>>(src, dst, idx2, idx1, node1, list2, cnts);
    k_pass1<<<EG, TB, 0, stream>>>(dst, idx1, list1, cnts);
    k_agg1<<<1024, 256, 0, stream>>>(in_feat, ew, src, dst, outcnt, idx1, list1, cnts, agg1c);
    k_h1<<<1024, 128, 0, stream>>>(W1, b1, incnt, node1, cnts, agg1c, h1c);
    k_agg2<<<512, 256, 0, stream>>>(ew, src, dst, outcnt, idx1, idx2, list2, cnts, h1c, agg2c);
    k_h2<<<512, 128, 0, stream>>>(W2, b2, incnt, node2, cnts, agg2c, h2c);
    k_agg3<<<64, 256, 0, stream>>>(ew, src, dst, outcnt, idx2, tgtmap, list3, cnts, h2c, agg3);
    k_out<<<1, 64, 0, stream>>>(W3, b3, incnt, tgtnode, agg3, out);
}

// Round 2
// 110.147 us; speedup vs baseline: 1.4023x; 1.4023x over previous
//
#include <hip/hip_runtime.h>

#define NND 50000
#define NED 500000
#define F0 64
#define F1 128
#define NCLS 4
#define NG 8

// capacities for compacted frontiers (expected: n2~80, e3~80, e2~800, n1~800, e1~8000)
#define N1CAP 8192
#define N2CAP 2048
#define E1CAP 65536
#define E2CAP 16384
#define E3CAP 4096

// cnts layout: [0]=n1, [1]=n2, [2]=e1, [3]=e2, [4]=e3

// degree counting + target marking (fused)
__global__ void k_degmark(const int* __restrict__ src, const int* __restrict__ dst,
                          unsigned* outcnt, unsigned* incnt,
                          const int* __restrict__ tnode, const unsigned* __restrict__ bnn,
                          int* tgtmap, int* tgtnode) {
    if (blockIdx.x == 0 && threadIdx.x < NG) {
        int g = threadIdx.x;
        // int64 batch_num_nodes has zero high words; int32 doesn't
        bool is64 = true;
        for (int k = 0; k < 4; k++) if (bnn[2 * k + 1] != 0u) { is64 = false; break; }
        long long off = 0;
        for (int k = 0; k < g; k++)
            off += is64 ? (long long)bnn[2 * k] : (long long)(int)bnn[k];
        int t = tnode[g] + (int)off;
        tgtmap[t] = g;
        tgtnode[g] = t;
    }
    int i = blockIdx.x * blockDim.x + threadIdx.x;
    if (i >= NED) return;
    atomicAdd(&outcnt[src[i]], 1u);
    atomicAdd(&incnt[dst[i]], 1u);
}

// ---- frontier passes with block-level compaction (kills same-address atomic serialization) ----

__global__ __launch_bounds__(1024) void k_pass3(const int* __restrict__ src,
                        const int* __restrict__ dst, const int* __restrict__ tgtmap,
                        int* idx2, int* node2, int* list3, unsigned* cnts) {
    __shared__ unsigned le, ln, ebase, nbase;
    if (threadIdx.x == 0) { le = 0; ln = 0; }
    __syncthreads();
    int i = blockIdx.x * blockDim.x + threadIdx.x;
    bool ehit = false, won = false; unsigned eoff = 0, noff = 0; int sreg = 0;
    if (i < NED) {
        int d = dst[i];
        if (tgtmap[d] >= 0) {
            ehit = true;
            eoff = atomicAdd(&le, 1u);
            int s = src[i];
            if (atomicCAS(&idx2[s], -1, -2) == -1) { won = true; sreg = s; noff = atomicAdd(&ln, 1u); }
        }
    }
    __syncthreads();
    if (threadIdx.x == 0) {
        ebase = le ? atomicAdd(&cnts[4], le) : 0u;
        nbase = ln ? atomicAdd(&cnts[1], ln) : 0u;
    }
    __syncthreads();
    if (ehit) { unsigned p = ebase + eoff; if (p < E3CAP) list3[p] = i; }
    if (won) {
        unsigned id = nbase + noff;
        if (id < N2CAP) { node2[id] = sreg; idx2[sreg] = (int)id; } else idx2[sreg] = -1;
    }
}

__global__ __launch_bounds__(1024) void k_pass2(const int* __restrict__ src,
                        const int* __restrict__ dst, const int* __restrict__ idx2,
                        int* idx1, int* node1, int* list2, unsigned* cnts) {
    __shared__ unsigned le, ln, ebase, nbase;
    if (threadIdx.x == 0) { le = 0; ln = 0; }
    __syncthreads();
    int i = blockIdx.x * blockDim.x + threadIdx.x;
    bool ehit = false, won = false; unsigned eoff = 0, noff = 0; int sreg = 0;
    if (i < NED) {
        int d = dst[i];
        if (idx2[d] >= 0) {
            ehit = true;
            eoff = atomicAdd(&le, 1u);
            int s = src[i];
            if (atomicCAS(&idx1[s], -1, -2) == -1) { won = true; sreg = s; noff = atomicAdd(&ln, 1u); }
        }
    }
    __syncthreads();
    if (threadIdx.x == 0) {
        ebase = le ? atomicAdd(&cnts[3], le) : 0u;
        nbase = ln ? atomicAdd(&cnts[0], ln) : 0u;
    }
    __syncthreads();
    if (ehit) { unsigned p = ebase + eoff; if (p < E2CAP) list2[p] = i; }
    if (won) {
        unsigned id = nbase + noff;
        if (id < N1CAP) { node1[id] = sreg; idx1[sreg] = (int)id; } else idx1[sreg] = -1;
    }
}

__global__ __launch_bounds__(1024) void k_pass1(const int* __restrict__ dst,
                        const int* __restrict__ idx1, int* list1, unsigned* cnts) {
    __shared__ unsigned le, ebase;
    if (threadIdx.x == 0) le = 0;
    __syncthreads();
    int i = blockIdx.x * blockDim.x + threadIdx.x;
    bool ehit = false; unsigned eoff = 0;
    if (i < NED && idx1[dst[i]] >= 0) { ehit = true; eoff = atomicAdd(&le, 1u); }
    __syncthreads();
    if (threadIdx.x == 0) ebase = le ? atomicAdd(&cnts[2], le) : 0u;
    __syncthreads();
    if (ehit) { unsigned p = ebase + eoff; if (p < E1CAP) list1[p] = i; }
}

// aggregate in_feat into agg1c over edges in list1; one 64-lane wave per edge
__global__ void k_agg1(const float* __restrict__ feat, const float* __restrict__ ew,
                       const int* __restrict__ src, const int* __restrict__ dst,
                       const unsigned* __restrict__ outcnt, const int* __restrict__ idx1,
                       const int* __restrict__ list1, const unsigned* __restrict__ cnts,
                       float* agg1c) {
    unsigned e1 = cnts[2]; if (e1 > E1CAP) e1 = E1CAP;
    int lane = threadIdx.x & 63;
    unsigned slot = (blockIdx.x * blockDim.x + threadIdx.x) >> 6;
    unsigned nslots = (gridDim.x * blockDim.x) >> 6;
    for (unsigned i = slot; i < e1; i += nslots) {
        int e = list1[i];
        int s = src[e], d = dst[e];
        int i1 = idx1[d]; if (i1 < 0) continue;
        float w = ew[e] * rsqrtf(fmaxf((float)outcnt[s], 1.f));
        atomicAdd(&agg1c[(size_t)i1 * F0 + lane], feat[(size_t)s * F0 + lane] * w);
    }
}

// h1 = relu(in_norm * agg1 @ W1 + b1)
__global__ void k_h1(const float* __restrict__ W1, const float* __restrict__ b1,
                     const unsigned* __restrict__ incnt, const int* __restrict__ node1,
                     const unsigned* __restrict__ cnts, const float* __restrict__ agg1c,
                     float* h1c) {
    __shared__ float a[F0];
    unsigned n1 = cnts[0]; if (n1 > N1CAP) n1 = N1CAP;
    int j = threadIdx.x;
    for (unsigned i = blockIdx.x; i < n1; i += gridDim.x) {
        int v = node1[i];
        float innorm = rsqrtf(fmaxf((float)incnt[v], 1.f));
        if (j < F0) a[j] = agg1c[(size_t)i * F0 + j] * innorm;
        __syncthreads();
        float acc = b1[j];
        #pragma unroll
        for (int k = 0; k < F0; k++) acc += a[k] * W1[k * F1 + j];
        h1c[(size_t)i * F1 + j] = fmaxf(acc, 0.f);
        __syncthreads();
    }
}

// aggregate h1 into agg2c over edges in list2; 128-thread group per edge
__global__ void k_agg2(const float* __restrict__ ew, const int* __restrict__ src,
                       const int* __restrict__ dst, const unsigned* __restrict__ outcnt,
                       const int* __restrict__ idx1, const int* __restrict__ idx2,
                       const int* __restrict__ list2, const unsigned* __restrict__ cnts,
                       const float* __restrict__ h1c, float* agg2c) {
    unsigned e2 = cnts[3]; if (e2 > E2CAP) e2 = E2CAP;
    int j = threadIdx.x & 127;
    unsigned slot = (blockIdx.x * blockDim.x + threadIdx.x) >> 7;
    unsigned nslots = (gridDim.x * blockDim.x) >> 7;
    for (unsigned i = slot; i < e2; i += nslots) {
        int e = list2[i];
        int s = src[e], d = dst[e];
        int i1 = idx1[s], i2 = idx2[d];
        if (i1 < 0 || i2 < 0) continue;
        float w = ew[e] * rsqrtf(fmaxf((float)outcnt[s], 1.f));
        atomicAdd(&agg2c[(size_t)i2 * F1 + j], h1c[(size_t)i1 * F1 + j] * w);
    }
}

// h2 = relu(in_norm * agg2 @ W2 + b2)
__global__ void k_h2(const float* __restrict__ W2, const float* __restrict__ b2,
                     const unsigned* __restrict__ incnt, const int* __restrict__ node2,
                     const unsigned* __restrict__ cnts, const float* __restrict__ agg2c,
                     float* h2c) {
    __shared__ float a[F1];
    unsigned n2 = cnts[1]; if (n2 > N2CAP) n2 = N2CAP;
    int j = threadIdx.x;
    for (unsigned i = blockIdx.x; i < n2; i += gridDim.x) {
        int v = node2[i];
        float innorm = rsqrtf(fmaxf((float)incnt[v], 1.f));
        a[j] = agg2c[(size_t)i * F1 + j] * innorm;
        __syncthreads();
        float acc = b2[j];
        #pragma unroll
        for (int k = 0; k < F1; k++) acc += a[k] * W2[k * F1 + j];
        h2c[(size_t)i * F1 + j] = fmaxf(acc, 0.f);
        __syncthreads();
    }
}

// layer-3 aggregation (LDS accumulator, single block) fused with final matmul
__global__ __launch_bounds__(1024) void k_agg3out(const float* __restrict__ ew,
                      const int* __restrict__ src, const int* __restrict__ dst,
                      const unsigned* __restrict__ outcnt, const int* __restrict__ idx2,
                      const int* __restrict__ tgtmap, const int* __restrict__ list3,
                      const unsigned* __restrict__ cnts, const float* __restrict__ h2c,
                      const unsigned* __restrict__ incnt, const int* __restrict__ tgtnode,
                      const float* __restrict__ W3, const float* __restrict__ b3,
                      float* out) {
    __shared__ float sagg[NG * F1];
    for (int t = threadIdx.x; t < NG * F1; t += blockDim.x) sagg[t] = 0.f;
    __syncthreads();
    unsigned e3 = cnts[4]; if (e3 > E3CAP) e3 = E3CAP;
    int j = threadIdx.x & 127;
    unsigned slot = threadIdx.x >> 7;   // 8 edge slots
    for (unsigned i = slot; i < e3; i += 8) {
        int e = list3[i];
        int s = src[e], d = dst[e];
        int i2 = idx2[s]; if (i2 < 0) continue;
        int g = tgtmap[d];
        float w = ew[e] * rsqrtf(fmaxf((float)outcnt[s], 1.f));
        atomicAdd(&sagg[g * F1 + j], h2c[(size_t)i2 * F1 + j] * w);
    }
    __syncthreads();
    int t = threadIdx.x;
    if (t < NG * NCLS) {
        int g = t >> 2, c = t & 3;
        float innorm = rsqrtf(fmaxf((float)incnt[tgtnode[g]], 1.f));
        float sm = 0.f;
        for (int k = 0; k < F1; k++) sm += sagg[g * F1 + k] * W3[k * NCLS + c];
        out[t] = sm * innorm + b3[c];
    }
}

extern "C" void kernel_launch(void* const* d_in, const int* in_sizes, int n_in,
                              void* d_out, int out_size, void* d_ws, size_t ws_size,
                              hipStream_t stream) {
    const float* in_feat = (const float*)d_in[0];
    const float* ew      = (const float*)d_in[1];
    const int*   src     = (const int*)d_in[2];
    const int*   dst     = (const int*)d_in[3];
    const unsigned* bnn  = (const unsigned*)d_in[4];
    const int*   tnode   = (const int*)d_in[5];
    const float* W1 = (const float*)d_in[6];
    const float* b1 = (const float*)d_in[7];
    const float* W2 = (const float*)d_in[8];
    const float* b2 = (const float*)d_in[9];
    const float* W3 = (const float*)d_in[10];
    const float* b3 = (const float*)d_in[11];
    float* out = (float*)d_out;
    (void)in_sizes; (void)n_in; (void)out_size; (void)ws_size;

    char* ws = (char*)d_ws;
    size_t o = 0;
    auto alloc = [&](size_t bytes) { size_t r = o; o += (bytes + 255) & ~(size_t)255; return r; };

    // --- zero-init region (contiguous) ---
    size_t zero_start = o;
    size_t off_outcnt = alloc((size_t)NND * 4);
    size_t off_incnt  = alloc((size_t)NND * 4);
    size_t off_cnts   = alloc(8 * 4);
    size_t off_agg1   = alloc((size_t)N1CAP * F0 * 4);
    size_t off_agg2   = alloc((size_t)N2CAP * F1 * 4);
    size_t zero_bytes = o - zero_start;
    // --- 0xFF-init region (contiguous) ---
    size_t ff_start = o;
    size_t off_tgtmap = alloc((size_t)NND * 4);
    size_t off_idx2   = alloc((size_t)NND * 4);
    size_t off_idx1   = alloc((size_t)NND * 4);
    size_t ff_bytes = o - ff_start;
    // --- write-before-read region ---
    size_t off_node2   = alloc((size_t)N2CAP * 4);
    size_t off_node1   = alloc((size_t)N1CAP * 4);
    size_t off_list3   = alloc((size_t)E3CAP * 4);
    size_t off_list2   = alloc((size_t)E2CAP * 4);
    size_t off_list1   = alloc((size_t)E1CAP * 4);
    size_t off_tgtnode = alloc((size_t)NG * 4);
    size_t off_h1      = alloc((size_t)N1CAP * F1 * 4);
    size_t off_h2      = alloc((size_t)N2CAP * F1 * 4);

    unsigned* outcnt  = (unsigned*)(ws + off_outcnt);
    unsigned* incnt   = (unsigned*)(ws + off_incnt);
    unsigned* cnts    = (unsigned*)(ws + off_cnts);
    float*    agg1c   = (float*)(ws + off_agg1);
    float*    agg2c   = (float*)(ws + off_agg2);
    int*      tgtmap  = (int*)(ws + off_tgtmap);
    int*      idx2    = (int*)(ws + off_idx2);
    int*      idx1    = (int*)(ws + off_idx1);
    int*      node2   = (int*)(ws + off_node2);
    int*      node1   = (int*)(ws + off_node1);
    int*      list3   = (int*)(ws + off_list3);
    int*      list2   = (int*)(ws + off_list2);
    int*      list1   = (int*)(ws + off_list1);
    int*      tgtnode = (int*)(ws + off_tgtnode);
    float*    h1c     = (float*)(ws + off_h1);
    float*    h2c     = (float*)(ws + off_h2);

    hipMemsetAsync(ws + zero_start, 0, zero_bytes, stream);
    hipMemsetAsync(ws + ff_start, 0xFF, ff_bytes, stream);

    const int EG256  = (NED + 255) / 256;
    const int EG1024 = (NED + 1023) / 1024;

    k_degmark<<<EG256, 256, 0, stream>>>(src, dst, outcnt, incnt, tnode, bnn, tgtmap, tgtnode);
    k_pass3<<<EG1024, 1024, 0, stream>>>(src, dst, tgtmap, idx2, node2, list3, cnts);
    k_pass2<<<EG1024, 1024, 0, stream>>>(src, dst, idx2, idx1, node1, list2, cnts);
    k_pass1<<<EG1024, 1024, 0, stream>>>(dst, idx1, list1, cnts);
    k_agg1<<<1024, 256, 0, stream>>>(in_feat, ew, src, dst, outcnt, idx1, list1, cnts, agg1c);
    k_h1<<<1024, 128, 0, stream>>>(W1, b1, incnt, node1, cnts, agg1c, h1c);
    k_agg2<<<512, 256, 0, stream>>>(ew, src, dst, outcnt, idx1, idx2, list2, cnts, h1c, agg2c);
    k_h2<<<512, 128, 0, stream>>>(W2, b2, incnt, node2, cnts, agg2c, h2c);
    k_agg3out<<<1, 1024, 0, stream>>>(ew, src, dst, outcnt, idx2, tgtmap, list3, cnts, h2c,
                                      incnt, tgtnode, W3, b3, out);
}

// Round 3
// 83.506 us; speedup vs baseline: 1.8497x; 1.3190x over previous
//
#include <hip/hip_runtime.h>

#define NND 50000
#define NED 500000
#define F0 64
#define F1 128
#define NCLS 4
#define NG 8

// capacities for compacted frontiers (expected: n2~80, e3~80, e2~800, n1~800, e1~8000)
#define N1CAP 4096
#define N2CAP 1024
#define E1CAP 32768
#define E2CAP 8192
#define E3CAP 2048

// cnts layout: [0]=n1, [1]=n2, [2]=e1, [3]=e2, [4]=e3

// mark target nodes; detect int32 vs int64 batch_num_nodes
__global__ void k_mark(const int* __restrict__ tnode, const unsigned* __restrict__ bnn,
                       int* tgtmap, int* tgtnode) {
    int g = threadIdx.x;
    if (g >= NG) return;
    bool is64 = true;
    for (int k = 0; k < 4; k++) if (bnn[2 * k + 1] != 0u) { is64 = false; break; }
    long long off = 0;
    for (int k = 0; k < g; k++)
        off += is64 ? (long long)bnn[2 * k] : (long long)(int)bnn[k];
    int t = tnode[g] + (int)off;
    tgtmap[t] = g;
    tgtnode[g] = t;
}

// ---- frontier passes: block-compacted edge lists, in-deg counted on hits
//      (priority dedupe: target > node2 > node1), need_out marked on hits ----

__global__ __launch_bounds__(256) void k_pass3(const int* __restrict__ src,
                        const int* __restrict__ dst, const int* __restrict__ tgtmap,
                        int* idx2, int* node2, int* list3, unsigned* cnts,
                        unsigned* incnt, unsigned char* need_out) {
    __shared__ unsigned le, ln, ebase, nbase;
    if (threadIdx.x == 0) { le = 0; ln = 0; }
    __syncthreads();
    int t = blockIdx.x * blockDim.x + threadIdx.x;
    int base = t * 4;
    bool ehit[4] = {false,false,false,false}, won[4] = {false,false,false,false};
    unsigned eoff[4], noff[4]; int sreg[4];
    if (base < NED) {
        int4 d4 = *(const int4*)(dst + base);
        int dd[4] = {d4.x, d4.y, d4.z, d4.w};
        #pragma unroll
        for (int k = 0; k < 4; k++) {
            int d = dd[k];
            if (tgtmap[d] >= 0) {
                ehit[k] = true;
                eoff[k] = atomicAdd(&le, 1u);
                atomicAdd(&incnt[d], 1u);          // in-deg for targets (counted here only)
                int s = src[base + k];
                need_out[s] = 1;
                if (atomicCAS(&idx2[s], -1, -2) == -1) {
                    won[k] = true; sreg[k] = s; noff[k] = atomicAdd(&ln, 1u);
                }
            }
        }
    }
    __syncthreads();
    if (threadIdx.x == 0) {
        ebase = le ? atomicAdd(&cnts[4], le) : 0u;
        nbase = ln ? atomicAdd(&cnts[1], ln) : 0u;
    }
    __syncthreads();
    #pragma unroll
    for (int k = 0; k < 4; k++) {
        if (ehit[k]) { unsigned p = ebase + eoff[k]; if (p < E3CAP) list3[p] = base + k; }
        if (won[k]) {
            unsigned id = nbase + noff[k];
            if (id < N2CAP) { node2[id] = sreg[k]; idx2[sreg[k]] = (int)id; }
            else idx2[sreg[k]] = -1;
        }
    }
}

__global__ __launch_bounds__(256) void k_pass2(const int* __restrict__ src,
                        const int* __restrict__ dst, const int* __restrict__ idx2,
                        const int* __restrict__ tgtmap, int* idx1, int* node1,
                        int* list2, unsigned* cnts, unsigned* incnt,
                        unsigned char* need_out) {
    __shared__ unsigned le, ln, ebase, nbase;
    if (threadIdx.x == 0) { le = 0; ln = 0; }
    __syncthreads();
    int t = blockIdx.x * blockDim.x + threadIdx.x;
    int base = t * 4;
    bool ehit[4] = {false,false,false,false}, won[4] = {false,false,false,false};
    unsigned eoff[4], noff[4]; int sreg[4];
    if (base < NED) {
        int4 d4 = *(const int4*)(dst + base);
        int dd[4] = {d4.x, d4.y, d4.z, d4.w};
        #pragma unroll
        for (int k = 0; k < 4; k++) {
            int d = dd[k];
            if (idx2[d] >= 0) {
                ehit[k] = true;
                eoff[k] = atomicAdd(&le, 1u);
                if (tgtmap[d] < 0) atomicAdd(&incnt[d], 1u);   // in-deg for node2 (not targets)
                int s = src[base + k];
                need_out[s] = 1;
                if (atomicCAS(&idx1[s], -1, -2) == -1) {
                    won[k] = true; sreg[k] = s; noff[k] = atomicAdd(&ln, 1u);
                }
            }
        }
    }
    __syncthreads();
    if (threadIdx.x == 0) {
        ebase = le ? atomicAdd(&cnts[3], le) : 0u;
        nbase = ln ? atomicAdd(&cnts[0], ln) : 0u;
    }
    __syncthreads();
    #pragma unroll
    for (int k = 0; k < 4; k++) {
        if (ehit[k]) { unsigned p = ebase + eoff[k]; if (p < E2CAP) list2[p] = base + k; }
        if (won[k]) {
            unsigned id = nbase + noff[k];
            if (id < N1CAP) { node1[id] = sreg[k]; idx1[sreg[k]] = (int)id; }
            else idx1[sreg[k]] = -1;
        }
    }
}

__global__ __launch_bounds__(256) void k_pass1(const int* __restrict__ src,
                        const int* __restrict__ dst, const int* __restrict__ idx1,
                        const int* __restrict__ idx2, const int* __restrict__ tgtmap,
                        int* list1, unsigned* cnts, unsigned* incnt,
                        unsigned char* need_out) {
    __shared__ unsigned le, ebase;
    if (threadIdx.x == 0) le = 0;
    __syncthreads();
    int t = blockIdx.x * blockDim.x + threadIdx.x;
    int base = t * 4;
    bool ehit[4] = {false,false,false,false};
    unsigned eoff[4];
    if (base < NED) {
        int4 d4 = *(const int4*)(dst + base);
        int dd[4] = {d4.x, d4.y, d4.z, d4.w};
        #pragma unroll
        for (int k = 0; k < 4; k++) {
            int d = dd[k];
            if (idx1[d] >= 0) {
                ehit[k] = true;
                eoff[k] = atomicAdd(&le, 1u);
                if (idx2[d] < 0 && tgtmap[d] < 0) atomicAdd(&incnt[d], 1u);  // node1-only in-deg
                need_out[src[base + k]] = 1;
            }
        }
    }
    __syncthreads();
    if (threadIdx.x == 0) ebase = le ? atomicAdd(&cnts[2], le) : 0u;
    __syncthreads();
    #pragma unroll
    for (int k = 0; k < 4; k++)
        if (ehit[k]) { unsigned p = ebase + eoff[k]; if (p < E1CAP) list1[p] = base + k; }
}

// filtered out-degree: count all edges whose source is marked need_out
__global__ __launch_bounds__(256) void k_deg(const int* __restrict__ src,
                        const unsigned char* __restrict__ need_out, unsigned* outcnt) {
    int t = blockIdx.x * blockDim.x + threadIdx.x;
    int base = t * 4;
    if (base >= NED) return;
    int4 s4 = *(const int4*)(src + base);
    int ss[4] = {s4.x, s4.y, s4.z, s4.w};
    #pragma unroll
    for (int k = 0; k < 4; k++)
        if (need_out[ss[k]]) atomicAdd(&outcnt[ss[k]], 1u);
}

// aggregate in_feat into agg1c over edges in list1; one 64-lane wave per edge
__global__ void k_agg1(const float* __restrict__ feat, const float* __restrict__ ew,
                       const int* __restrict__ src, const int* __restrict__ dst,
                       const unsigned* __restrict__ outcnt, const int* __restrict__ idx1,
                       const int* __restrict__ list1, const unsigned* __restrict__ cnts,
                       float* agg1c) {
    unsigned e1 = cnts[2]; if (e1 > E1CAP) e1 = E1CAP;
    int lane = threadIdx.x & 63;
    unsigned slot = (blockIdx.x * blockDim.x + threadIdx.x) >> 6;
    unsigned nslots = (gridDim.x * blockDim.x) >> 6;
    for (unsigned i = slot; i < e1; i += nslots) {
        int e = list1[i];
        int s = src[e], d = dst[e];
        int i1 = idx1[d]; if (i1 < 0) continue;
        float w = ew[e] * rsqrtf(fmaxf((float)outcnt[s], 1.f));
        atomicAdd(&agg1c[(size_t)i1 * F0 + lane], feat[(size_t)s * F0 + lane] * w);
    }
}

// h1 = relu(in_norm * agg1 @ W1 + b1)
__global__ void k_h1(const float* __restrict__ W1, const float* __restrict__ b1,
                     const unsigned* __restrict__ incnt, const int* __restrict__ node1,
                     const unsigned* __restrict__ cnts, const float* __restrict__ agg1c,
                     float* h1c) {
    __shared__ float a[F0];
    unsigned n1 = cnts[0]; if (n1 > N1CAP) n1 = N1CAP;
    int j = threadIdx.x;
    for (unsigned i = blockIdx.x; i < n1; i += gridDim.x) {
        int v = node1[i];
        float innorm = rsqrtf(fmaxf((float)incnt[v], 1.f));
        if (j < F0) a[j] = agg1c[(size_t)i * F0 + j] * innorm;
        __syncthreads();
        float acc = b1[j];
        #pragma unroll
        for (int k = 0; k < F0; k++) acc += a[k] * W1[k * F1 + j];
        h1c[(size_t)i * F1 + j] = fmaxf(acc, 0.f);
        __syncthreads();
    }
}

// aggregate h1 into agg2c over edges in list2; 128-thread group per edge
__global__ void k_agg2(const float* __restrict__ ew, const int* __restrict__ src,
                       const int* __restrict__ dst, const unsigned* __restrict__ outcnt,
                       const int* __restrict__ idx1, const int* __restrict__ idx2,
                       const int* __restrict__ list2, const unsigned* __restrict__ cnts,
                       const float* __restrict__ h1c, float* agg2c) {
    unsigned e2 = cnts[3]; if (e2 > E2CAP) e2 = E2CAP;
    int j = threadIdx.x & 127;
    unsigned slot = (blockIdx.x * blockDim.x + threadIdx.x) >> 7;
    unsigned nslots = (gridDim.x * blockDim.x) >> 7;
    for (unsigned i = slot; i < e2; i += nslots) {
        int e = list2[i];
        int s = src[e], d = dst[e];
        int i1 = idx1[s], i2 = idx2[d];
        if (i1 < 0 || i2 < 0) continue;
        float w = ew[e] * rsqrtf(fmaxf((float)outcnt[s], 1.f));
        atomicAdd(&agg2c[(size_t)i2 * F1 + j], h1c[(size_t)i1 * F1 + j] * w);
    }
}

// h2 = relu(in_norm * agg2 @ W2 + b2)
__global__ void k_h2(const float* __restrict__ W2, const float* __restrict__ b2,
                     const unsigned* __restrict__ incnt, const int* __restrict__ node2,
                     const unsigned* __restrict__ cnts, const float* __restrict__ agg2c,
                     float* h2c) {
    __shared__ float a[F1];
    unsigned n2 = cnts[1]; if (n2 > N2CAP) n2 = N2CAP;
    int j = threadIdx.x;
    for (unsigned i = blockIdx.x; i < n2; i += gridDim.x) {
        int v = node2[i];
        float innorm = rsqrtf(fmaxf((float)incnt[v], 1.f));
        a[j] = agg2c[(size_t)i * F1 + j] * innorm;
        __syncthreads();
        float acc = b2[j];
        #pragma unroll
        for (int k = 0; k < F1; k++) acc += a[k] * W2[k * F1 + j];
        h2c[(size_t)i * F1 + j] = fmaxf(acc, 0.f);
        __syncthreads();
    }
}

// layer-3 aggregation (LDS accumulator, single block) fused with final matmul
__global__ __launch_bounds__(1024) void k_agg3out(const float* __restrict__ ew,
                      const int* __restrict__ src, const int* __restrict__ dst,
                      const unsigned* __restrict__ outcnt, const int* __restrict__ idx2,
                      const int* __restrict__ tgtmap, const int* __restrict__ list3,
                      const unsigned* __restrict__ cnts, const float* __restrict__ h2c,
                      const unsigned* __restrict__ incnt, const int* __restrict__ tgtnode,
                      const float* __restrict__ W3, const float* __restrict__ b3,
                      float* out) {
    __shared__ float sagg[NG * F1];
    for (int t = threadIdx.x; t < NG * F1; t += blockDim.x) sagg[t] = 0.f;
    __syncthreads();
    unsigned e3 = cnts[4]; if (e3 > E3CAP) e3 = E3CAP;
    int j = threadIdx.x & 127;
    unsigned slot = threadIdx.x >> 7;   // 8 edge slots
    for (unsigned i = slot; i < e3; i += 8) {
        int e = list3[i];
        int s = src[e], d = dst[e];
        int i2 = idx2[s]; if (i2 < 0) continue;
        int g = tgtmap[d];
        float w = ew[e] * rsqrtf(fmaxf((float)outcnt[s], 1.f));
        atomicAdd(&sagg[g * F1 + j], h2c[(size_t)i2 * F1 + j] * w);
    }
    __syncthreads();
    int t = threadIdx.x;
    if (t < NG * NCLS) {
        int g = t >> 2, c = t & 3;
        float innorm = rsqrtf(fmaxf((float)incnt[tgtnode[g]], 1.f));
        float sm = 0.f;
        for (int k = 0; k < F1; k++) sm += sagg[g * F1 + k] * W3[k * NCLS + c];
        out[t] = sm * innorm + b3[c];
    }
}

extern "C" void kernel_launch(void* const* d_in, const int* in_sizes, int n_in,
                              void* d_out, int out_size, void* d_ws, size_t ws_size,
                              hipStream_t stream) {
    const float* in_feat = (const float*)d_in[0];
    const float* ew      = (const float*)d_in[1];
    const int*   src     = (const int*)d_in[2];
    const int*   dst     = (const int*)d_in[3];
    const unsigned* bnn  = (const unsigned*)d_in[4];
    const int*   tnode   = (const int*)d_in[5];
    const float* W1 = (const float*)d_in[6];
    const float* b1 = (const float*)d_in[7];
    const float* W2 = (const float*)d_in[8];
    const float* b2 = (const float*)d_in[9];
    const float* W3 = (const float*)d_in[10];
    const float* b3 = (const float*)d_in[11];
    float* out = (float*)d_out;
    (void)in_sizes; (void)n_in; (void)out_size; (void)ws_size;

    char* ws = (char*)d_ws;
    size_t o = 0;
    auto alloc = [&](size_t bytes) { size_t r = o; o += (bytes + 255) & ~(size_t)255; return r; };

    // --- zero-init region (contiguous) ---
    size_t zero_start = o;
    size_t off_outcnt = alloc((size_t)NND * 4);
    size_t off_incnt  = alloc((size_t)NND * 4);
    size_t off_cnts   = alloc(8 * 4);
    size_t off_agg1   = alloc((size_t)N1CAP * F0 * 4);
    size_t off_agg2   = alloc((size_t)N2CAP * F1 * 4);
    size_t off_need   = alloc((size_t)NND);
    size_t zero_bytes = o - zero_start;
    // --- 0xFF-init region (contiguous) ---
    size_t ff_start = o;
    size_t off_tgtmap = alloc((size_t)NND * 4);
    size_t off_idx2   = alloc((size_t)NND * 4);
    size_t off_idx1   = alloc((size_t)NND * 4);
    size_t ff_bytes = o - ff_start;
    // --- write-before-read region ---
    size_t off_node2   = alloc((size_t)N2CAP * 4);
    size_t off_node1   = alloc((size_t)N1CAP * 4);
    size_t off_list3   = alloc((size_t)E3CAP * 4);
    size_t off_list2   = alloc((size_t)E2CAP * 4);
    size_t off_list1   = alloc((size_t)E1CAP * 4);
    size_t off_tgtnode = alloc((size_t)NG * 4);
    size_t off_h1      = alloc((size_t)N1CAP * F1 * 4);
    size_t off_h2      = alloc((size_t)N2CAP * F1 * 4);

    unsigned* outcnt  = (unsigned*)(ws + off_outcnt);
    unsigned* incnt   = (unsigned*)(ws + off_incnt);
    unsigned* cnts    = (unsigned*)(ws + off_cnts);
    float*    agg1c   = (float*)(ws + off_agg1);
    float*    agg2c   = (float*)(ws + off_agg2);
    unsigned char* need_out = (unsigned char*)(ws + off_need);
    int*      tgtmap  = (int*)(ws + off_tgtmap);
    int*      idx2    = (int*)(ws + off_idx2);
    int*      idx1    = (int*)(ws + off_idx1);
    int*      node2   = (int*)(ws + off_node2);
    int*      node1   = (int*)(ws + off_node1);
    int*      list3   = (int*)(ws + off_list3);
    int*      list2   = (int*)(ws + off_list2);
    int*      list1   = (int*)(ws + off_list1);
    int*      tgtnode = (int*)(ws + off_tgtnode);
    float*    h1c     = (float*)(ws + off_h1);
    float*    h2c     = (float*)(ws + off_h2);

    hipMemsetAsync(ws + zero_start, 0, zero_bytes, stream);
    hipMemsetAsync(ws + ff_start, 0xFF, ff_bytes, stream);

    const int EG4 = (NED / 4 + 255) / 256;   // int4-vectorized full-edge scans

    k_mark<<<1, 64, 0, stream>>>(tnode, bnn, tgtmap, tgtnode);
    k_pass3<<<EG4, 256, 0, stream>>>(src, dst, tgtmap, idx2, node2, list3, cnts, incnt, need_out);
    k_pass2<<<EG4, 256, 0, stream>>>(src, dst, idx2, tgtmap, idx1, node1, list2, cnts, incnt, need_out);
    k_pass1<<<EG4, 256, 0, stream>>>(src, dst, idx1, idx2, tgtmap, list1, cnts, incnt, need_out);
    k_deg<<<EG4, 256, 0, stream>>>(src, need_out, outcnt);
    k_agg1<<<512, 256, 0, stream>>>(in_feat, ew, src, dst, outcnt, idx1, list1, cnts, agg1c);
    k_h1<<<512, 128, 0, stream>>>(W1, b1, incnt, node1, cnts, agg1c, h1c);
    k_agg2<<<128, 256, 0, stream>>>(ew, src, dst, outcnt, idx1, idx2, list2, cnts, h1c, agg2c);
    k_h2<<<128, 128, 0, stream>>>(W2, b2, incnt, node2, cnts, agg2c, h2c);
    k_agg3out<<<1, 1024, 0, stream>>>(ew, src, dst, outcnt, idx2, tgtmap, list3, cnts, h2c,
                                      incnt, tgtnode, W3, b3, out);
}

// Round 4
// 79.119 us; speedup vs baseline: 1.9522x; 1.0554x over previous
//
#include <hip/hip_runtime.h>

#define NND 50000
#define NED 500000
#define F0 64
#define F1 128
#define NCLS 4
#define NG 8

// capacities for compacted frontiers (expected: n2~80, e3~80, e2~800, n1~800, e1~8000)
#define N1CAP 4096
#define N2CAP 1024
#define E1CAP 32768
#define E2CAP 8192
#define E3CAP 2048

// cnts layout: [0]=n1, [1]=n2, [2]=e1, [3]=e2, [4]=e3

// compute the 8 global target node ids inline (uniform; replaces tgtmap array)
__device__ __forceinline__ void load_targets(const int* __restrict__ tnode,
                                             const unsigned* __restrict__ bnn,
                                             int* t) {
    // int64 batch_num_nodes has zero high words; int32 doesn't (values ~6250)
    bool is64 = true;
    #pragma unroll
    for (int k = 0; k < 4; k++) if (bnn[2 * k + 1] != 0u) { is64 = false; break; }
    long long off = 0;
    #pragma unroll
    for (int g = 0; g < NG; g++) {
        t[g] = tnode[g] + (int)off;
        off += is64 ? (long long)bnn[2 * g] : (long long)(int)bnn[g];
    }
}

__device__ __forceinline__ int tgt_of(int d, const int* t) {
    int g = -1;
    #pragma unroll
    for (int k = 0; k < NG; k++) if (d == t[k]) g = k;
    return g;
}

// workspace init: zero region + 0xFF region, 16B vector stores
__global__ __launch_bounds__(256) void k_init(char* ws, unsigned zw, unsigned foff, unsigned fw) {
    unsigned t = blockIdx.x * blockDim.x + threadIdx.x;
    if (t < zw) ((uint4*)ws)[t] = make_uint4(0u, 0u, 0u, 0u);
    if (t < fw) ((uint4*)(ws + foff))[t] = make_uint4(~0u, ~0u, ~0u, ~0u);
}

// ---- frontier passes: block-compacted edge lists, in-deg counted on hits
//      (priority dedupe: target > node2 > node1), need_out marked on hits ----

__global__ __launch_bounds__(256) void k_pass3(const int* __restrict__ src,
                        const int* __restrict__ dst, const int* __restrict__ tnode,
                        const unsigned* __restrict__ bnn, int* idx2, int* node2,
                        int* list3, unsigned* cnts, unsigned* incnt,
                        unsigned char* need_out) {
    int tg[NG]; load_targets(tnode, bnn, tg);
    __shared__ unsigned le, ln, ebase, nbase;
    if (threadIdx.x == 0) { le = 0; ln = 0; }
    __syncthreads();
    int t = blockIdx.x * blockDim.x + threadIdx.x;
    int base = t * 4;
    bool ehit[4] = {false,false,false,false}, won[4] = {false,false,false,false};
    unsigned eoff[4], noff[4]; int sreg[4];
    if (base < NED) {
        int4 d4 = *(const int4*)(dst + base);
        int dd[4] = {d4.x, d4.y, d4.z, d4.w};
        #pragma unroll
        for (int k = 0; k < 4; k++) {
            int d = dd[k];
            if (tgt_of(d, tg) >= 0) {
                ehit[k] = true;
                eoff[k] = atomicAdd(&le, 1u);
                atomicAdd(&incnt[d], 1u);          // in-deg for targets (counted here only)
                int s = src[base + k];
                need_out[s] = 1;
                if (atomicCAS(&idx2[s], -1, -2) == -1) {
                    won[k] = true; sreg[k] = s; noff[k] = atomicAdd(&ln, 1u);
                }
            }
        }
    }
    __syncthreads();
    if (threadIdx.x == 0) {
        ebase = le ? atomicAdd(&cnts[4], le) : 0u;
        nbase = ln ? atomicAdd(&cnts[1], ln) : 0u;
    }
    __syncthreads();
    #pragma unroll
    for (int k = 0; k < 4; k++) {
        if (ehit[k]) { unsigned p = ebase + eoff[k]; if (p < E3CAP) list3[p] = base + k; }
        if (won[k]) {
            unsigned id = nbase + noff[k];
            if (id < N2CAP) { node2[id] = sreg[k]; idx2[sreg[k]] = (int)id; }
            else idx2[sreg[k]] = -1;
        }
    }
}

__global__ __launch_bounds__(256) void k_pass2(const int* __restrict__ src,
                        const int* __restrict__ dst, const int* __restrict__ idx2,
                        const int* __restrict__ tnode, const unsigned* __restrict__ bnn,
                        int* idx1, int* node1, int* list2, unsigned* cnts,
                        unsigned* incnt, unsigned char* need_out) {
    int tg[NG]; load_targets(tnode, bnn, tg);
    __shared__ unsigned le, ln, ebase, nbase;
    if (threadIdx.x == 0) { le = 0; ln = 0; }
    __syncthreads();
    int t = blockIdx.x * blockDim.x + threadIdx.x;
    int base = t * 4;
    bool ehit[4] = {false,false,false,false}, won[4] = {false,false,false,false};
    unsigned eoff[4], noff[4]; int sreg[4];
    if (base < NED) {
        int4 d4 = *(const int4*)(dst + base);
        int dd[4] = {d4.x, d4.y, d4.z, d4.w};
        #pragma unroll
        for (int k = 0; k < 4; k++) {
            int d = dd[k];
            if (idx2[d] >= 0) {
                ehit[k] = true;
                eoff[k] = atomicAdd(&le, 1u);
                if (tgt_of(d, tg) < 0) atomicAdd(&incnt[d], 1u);   // node2 in-deg (not targets)
                int s = src[base + k];
                need_out[s] = 1;
                if (atomicCAS(&idx1[s], -1, -2) == -1) {
                    won[k] = true; sreg[k] = s; noff[k] = atomicAdd(&ln, 1u);
                }
            }
        }
    }
    __syncthreads();
    if (threadIdx.x == 0) {
        ebase = le ? atomicAdd(&cnts[3], le) : 0u;
        nbase = ln ? atomicAdd(&cnts[0], ln) : 0u;
    }
    __syncthreads();
    #pragma unroll
    for (int k = 0; k < 4; k++) {
        if (ehit[k]) { unsigned p = ebase + eoff[k]; if (p < E2CAP) list2[p] = base + k; }
        if (won[k]) {
            unsigned id = nbase + noff[k];
            if (id < N1CAP) { node1[id] = sreg[k]; idx1[sreg[k]] = (int)id; }
            else idx1[sreg[k]] = -1;
        }
    }
}

__global__ __launch_bounds__(256) void k_pass1(const int* __restrict__ src,
                        const int* __restrict__ dst, const int* __restrict__ idx1,
                        const int* __restrict__ idx2, const int* __restrict__ tnode,
                        const unsigned* __restrict__ bnn, int* list1, unsigned* cnts,
                        unsigned* incnt, unsigned char* need_out) {
    int tg[NG]; load_targets(tnode, bnn, tg);
    __shared__ unsigned le, ebase;
    if (threadIdx.x == 0) le = 0;
    __syncthreads();
    int t = blockIdx.x * blockDim.x + threadIdx.x;
    int base = t * 4;
    bool ehit[4] = {false,false,false,false};
    unsigned eoff[4];
    if (base < NED) {
        int4 d4 = *(const int4*)(dst + base);
        int dd[4] = {d4.x, d4.y, d4.z, d4.w};
        #pragma unroll
        for (int k = 0; k < 4; k++) {
            int d = dd[k];
            if (idx1[d] >= 0) {
                ehit[k] = true;
                eoff[k] = atomicAdd(&le, 1u);
                if (idx2[d] < 0 && tgt_of(d, tg) < 0) atomicAdd(&incnt[d], 1u);  // node1-only
                need_out[src[base + k]] = 1;
            }
        }
    }
    __syncthreads();
    if (threadIdx.x == 0) ebase = le ? atomicAdd(&cnts[2], le) : 0u;
    __syncthreads();
    #pragma unroll
    for (int k = 0; k < 4; k++)
        if (ehit[k]) { unsigned p = ebase + eoff[k]; if (p < E1CAP) list1[p] = base + k; }
}

// filtered out-degree: count all edges whose source is marked need_out
__global__ __launch_bounds__(256) void k_deg(const int* __restrict__ src,
                        const unsigned char* __restrict__ need_out, unsigned* outcnt) {
    int t = blockIdx.x * blockDim.x + threadIdx.x;
    int base = t * 4;
    if (base >= NED) return;
    int4 s4 = *(const int4*)(src + base);
    int ss[4] = {s4.x, s4.y, s4.z, s4.w};
    #pragma unroll
    for (int k = 0; k < 4; k++)
        if (need_out[ss[k]]) atomicAdd(&outcnt[ss[k]], 1u);
}

// aggregate in_feat into agg1c over edges in list1; one 64-lane wave per edge
__global__ void k_agg1(const float* __restrict__ feat, const float* __restrict__ ew,
                       const int* __restrict__ src, const int* __restrict__ dst,
                       const unsigned* __restrict__ outcnt, const int* __restrict__ idx1,
                       const int* __restrict__ list1, const unsigned* __restrict__ cnts,
                       float* agg1c) {
    unsigned e1 = cnts[2]; if (e1 > E1CAP) e1 = E1CAP;
    int lane = threadIdx.x & 63;
    unsigned slot = (blockIdx.x * blockDim.x + threadIdx.x) >> 6;
    unsigned nslots = (gridDim.x * blockDim.x) >> 6;
    for (unsigned i = slot; i < e1; i += nslots) {
        int e = list1[i];
        int s = src[e], d = dst[e];
        int i1 = idx1[d]; if (i1 < 0) continue;
        float w = ew[e] * rsqrtf(fmaxf((float)outcnt[s], 1.f));
        atomicAdd(&agg1c[(size_t)i1 * F0 + lane], feat[(size_t)s * F0 + lane] * w);
    }
}

// h1 = relu(in_norm * agg1 @ W1 + b1)
__global__ void k_h1(const float* __restrict__ W1, const float* __restrict__ b1,
                     const unsigned* __restrict__ incnt, const int* __restrict__ node1,
                     const unsigned* __restrict__ cnts, const float* __restrict__ agg1c,
                     float* h1c) {
    __shared__ float a[F0];
    unsigned n1 = cnts[0]; if (n1 > N1CAP) n1 = N1CAP;
    int j = threadIdx.x;
    for (unsigned i = blockIdx.x; i < n1; i += gridDim.x) {
        int v = node1[i];
        float innorm = rsqrtf(fmaxf((float)incnt[v], 1.f));
        if (j < F0) a[j] = agg1c[(size_t)i * F0 + j] * innorm;
        __syncthreads();
        float acc = b1[j];
        #pragma unroll
        for (int k = 0; k < F0; k++) acc += a[k] * W1[k * F1 + j];
        h1c[(size_t)i * F1 + j] = fmaxf(acc, 0.f);
        __syncthreads();
    }
}

// aggregate h1 into agg2c over edges in list2; 128-thread group per edge
__global__ void k_agg2(const float* __restrict__ ew, const int* __restrict__ src,
                       const int* __restrict__ dst, const unsigned* __restrict__ outcnt,
                       const int* __restrict__ idx1, const int* __restrict__ idx2,
                       const int* __restrict__ list2, const unsigned* __restrict__ cnts,
                       const float* __restrict__ h1c, float* agg2c) {
    unsigned e2 = cnts[3]; if (e2 > E2CAP) e2 = E2CAP;
    int j = threadIdx.x & 127;
    unsigned slot = (blockIdx.x * blockDim.x + threadIdx.x) >> 7;
    unsigned nslots = (gridDim.x * blockDim.x) >> 7;
    for (unsigned i = slot; i < e2; i += nslots) {
        int e = list2[i];
        int s = src[e], d = dst[e];
        int i1 = idx1[s], i2 = idx2[d];
        if (i1 < 0 || i2 < 0) continue;
        float w = ew[e] * rsqrtf(fmaxf((float)outcnt[s], 1.f));
        atomicAdd(&agg2c[(size_t)i2 * F1 + j], h1c[(size_t)i1 * F1 + j] * w);
    }
}

// h2 = relu(in_norm * agg2 @ W2 + b2)
__global__ void k_h2(const float* __restrict__ W2, const float* __restrict__ b2,
                     const unsigned* __restrict__ incnt, const int* __restrict__ node2,
                     const unsigned* __restrict__ cnts, const float* __restrict__ agg2c,
                     float* h2c) {
    __shared__ float a[F1];
    unsigned n2 = cnts[1]; if (n2 > N2CAP) n2 = N2CAP;
    int j = threadIdx.x;
    for (unsigned i = blockIdx.x; i < n2; i += gridDim.x) {
        int v = node2[i];
        float innorm = rsqrtf(fmaxf((float)incnt[v], 1.f));
        a[j] = agg2c[(size_t)i * F1 + j] * innorm;
        __syncthreads();
        float acc = b2[j];
        #pragma unroll
        for (int k = 0; k < F1; k++) acc += a[k] * W2[k * F1 + j];
        h2c[(size_t)i * F1 + j] = fmaxf(acc, 0.f);
        __syncthreads();
    }
}

// layer-3 aggregation (LDS accumulator, single block) fused with final matmul
__global__ __launch_bounds__(1024) void k_agg3out(const float* __restrict__ ew,
                      const int* __restrict__ src, const int* __restrict__ dst,
                      const unsigned* __restrict__ outcnt, const int* __restrict__ idx2,
                      const int* __restrict__ tnode, const unsigned* __restrict__ bnn,
                      const int* __restrict__ list3, const unsigned* __restrict__ cnts,
                      const float* __restrict__ h2c, const unsigned* __restrict__ incnt,
                      const float* __restrict__ W3, const float* __restrict__ b3,
                      float* out) {
    int tg[NG]; load_targets(tnode, bnn, tg);
    __shared__ float sagg[NG * F1];
    for (int t = threadIdx.x; t < NG * F1; t += blockDim.x) sagg[t] = 0.f;
    __syncthreads();
    unsigned e3 = cnts[4]; if (e3 > E3CAP) e3 = E3CAP;
    int j = threadIdx.x & 127;
    unsigned slot = threadIdx.x >> 7;   // 8 edge slots
    for (unsigned i = slot; i < e3; i += 8) {
        int e = list3[i];
        int s = src[e], d = dst[e];
        int i2 = idx2[s]; if (i2 < 0) continue;
        int g = tgt_of(d, tg);
        float w = ew[e] * rsqrtf(fmaxf((float)outcnt[s], 1.f));
        atomicAdd(&sagg[g * F1 + j], h2c[(size_t)i2 * F1 + j] * w);
    }
    __syncthreads();
    int t = threadIdx.x;
    if (t < NG * NCLS) {
        int g = t >> 2, c = t & 3;
        float innorm = rsqrtf(fmaxf((float)incnt[tg[g]], 1.f));
        float sm = 0.f;
        for (int k = 0; k < F1; k++) sm += sagg[g * F1 + k] * W3[k * NCLS + c];
        out[t] = sm * innorm + b3[c];
    }
}

extern "C" void kernel_launch(void* const* d_in, const int* in_sizes, int n_in,
                              void* d_out, int out_size, void* d_ws, size_t ws_size,
                              hipStream_t stream) {
    const float* in_feat = (const float*)d_in[0];
    const float* ew      = (const float*)d_in[1];
    const int*   src     = (const int*)d_in[2];
    const int*   dst     = (const int*)d_in[3];
    const unsigned* bnn  = (const unsigned*)d_in[4];
    const int*   tnode   = (const int*)d_in[5];
    const float* W1 = (const float*)d_in[6];
    const float* b1 = (const float*)d_in[7];
    const float* W2 = (const float*)d_in[8];
    const float* b2 = (const float*)d_in[9];
    const float* W3 = (const float*)d_in[10];
    const float* b3 = (const float*)d_in[11];
    float* out = (float*)d_out;
    (void)in_sizes; (void)n_in; (void)out_size; (void)ws_size;

    char* ws = (char*)d_ws;
    size_t o = 0;
    auto alloc = [&](size_t bytes) { size_t r = o; o += (bytes + 255) & ~(size_t)255; return r; };

    // --- zero-init region (contiguous, starts at 0) ---
    size_t off_outcnt = alloc((size_t)NND * 4);
    size_t off_incnt  = alloc((size_t)NND * 4);
    size_t off_cnts   = alloc(8 * 4);
    size_t off_agg1   = alloc((size_t)N1CAP * F0 * 4);
    size_t off_agg2   = alloc((size_t)N2CAP * F1 * 4);
    size_t off_need   = alloc((size_t)NND);
    size_t zero_bytes = o;
    // --- 0xFF-init region (contiguous) ---
    size_t ff_start = o;
    size_t off_idx2   = alloc((size_t)NND * 4);
    size_t off_idx1   = alloc((size_t)NND * 4);
    size_t ff_bytes = o - ff_start;
    // --- write-before-read region ---
    size_t off_node2   = alloc((size_t)N2CAP * 4);
    size_t off_node1   = alloc((size_t)N1CAP * 4);
    size_t off_list3   = alloc((size_t)E3CAP * 4);
    size_t off_list2   = alloc((size_t)E2CAP * 4);
    size_t off_list1   = alloc((size_t)E1CAP * 4);
    size_t off_h1      = alloc((size_t)N1CAP * F1 * 4);
    size_t off_h2      = alloc((size_t)N2CAP * F1 * 4);

    unsigned* outcnt  = (unsigned*)(ws + off_outcnt);
    unsigned* incnt   = (unsigned*)(ws + off_incnt);
    unsigned* cnts    = (unsigned*)(ws + off_cnts);
    float*    agg1c   = (float*)(ws + off_agg1);
    float*    agg2c   = (float*)(ws + off_agg2);
    unsigned char* need_out = (unsigned char*)(ws + off_need);
    int*      idx2    = (int*)(ws + off_idx2);
    int*      idx1    = (int*)(ws + off_idx1);
    int*      node2   = (int*)(ws + off_node2);
    int*      node1   = (int*)(ws + off_node1);
    int*      list3   = (int*)(ws + off_list3);
    int*      list2   = (int*)(ws + off_list2);
    int*      list1   = (int*)(ws + off_list1);
    float*    h1c     = (float*)(ws + off_h1);
    float*    h2c     = (float*)(ws + off_h2);

    unsigned zw = (unsigned)(zero_bytes / 16);
    unsigned fw = (unsigned)(ff_bytes / 16);
    unsigned iw = zw > fw ? zw : fw;
    k_init<<<(iw + 255) / 256, 256, 0, stream>>>(ws, zw, (unsigned)ff_start, fw);

    const int EG4 = (NED / 4 + 255) / 256;   // int4-vectorized full-edge scans

    k_pass3<<<EG4, 256, 0, stream>>>(src, dst, tnode, bnn, idx2, node2, list3, cnts, incnt, need_out);
    k_pass2<<<EG4, 256, 0, stream>>>(src, dst, idx2, tnode, bnn, idx1, node1, list2, cnts, incnt, need_out);
    k_pass1<<<EG4, 256, 0, stream>>>(src, dst, idx1, idx2, tnode, bnn, list1, cnts, incnt, need_out);
    k_deg<<<EG4, 256, 0, stream>>>(src, need_out, outcnt);
    k_agg1<<<512, 256, 0, stream>>>(in_feat, ew, src, dst, outcnt, idx1, list1, cnts, agg1c);
    k_h1<<<512, 128, 0, stream>>>(W1, b1, incnt, node1, cnts, agg1c, h1c);
    k_agg2<<<128, 256, 0, stream>>>(ew, src, dst, outcnt, idx1, idx2, list2, cnts, h1c, agg2c);
    k_h2<<<128, 128, 0, stream>>>(W2, b2, incnt, node2, cnts, agg2c, h2c);
    k_agg3out<<<1, 1024, 0, stream>>>(ew, src, dst, outcnt, idx2, tnode, bnn, list3, cnts, h2c,
                                      incnt, W3, b3, out);
}